// Round 14
// baseline (1285.179 us; speedup 1.0000x reference)
//
#include <hip/hip_runtime.h>
#include <hip/hip_bf16.h>
#include <math.h>

// ---------------- static problem config ----------------
#define NKEYS 13294
#define BATCH 2
#define MROWS (BATCH * NKEYS)   // 26588
#define EDIM  256
#define FDIM  1024
#define EPSV  1e-5f

typedef __bf16 bf16x8 __attribute__((ext_vector_type(8)));
typedef float  f32x4  __attribute__((ext_vector_type(4)));
typedef float  f32x2  __attribute__((ext_vector_type(2)));

__device__ __forceinline__ void async16(const void* g, void* l) {
    __builtin_amdgcn_global_load_lds(
        (const __attribute__((address_space(1))) void*)g,
        (__attribute__((address_space(3))) void*)l, 16, 0, 0);
}

// ---------------- bf16 MFMA GEMM (BM=128 x BN=128, waves 2x2 of 64x64, dbuf) ----------------
// XCD swizzle kept (~90 us aggregate win, R10/R11).
// MODE 1: split fused store (N=640): col<256 -> v_bf head-major bf16;
//         col<512 -> o_off bf16 (stride 256); else -> o_aw bf16 (stride 128).
// MODE 3: bf16 out + ReLU (stride N).
template<int MODE>
__global__ __launch_bounds__(256, 4) void gemm_mfma_k(
    const __hip_bfloat16* __restrict__ A, const __hip_bfloat16* __restrict__ WT,
    const float* __restrict__ bias, __hip_bfloat16* __restrict__ Cout,
    int M, int N, int K,
    __hip_bfloat16* __restrict__ o_vb, __hip_bfloat16* __restrict__ o_off,
    __hip_bfloat16* __restrict__ o_aw)
{
    constexpr int BM = 128, BN = 128, BKc = 32;
    constexpr int SMX = (BM + BN) * BKc;           // 8192 elems = 16 KB / buffer
    __shared__ __hip_bfloat16 smem[2 * SMX];       // 32 KB

    // ---- XCD-aware tile swizzle ----
    const int gx = gridDim.x, nb = gx * gridDim.y;
    int bxi = blockIdx.x, byi = blockIdx.y;
    if ((nb & 7) == 0) {
        const int id   = byi * gx + bxi;
        const int tile = (id & 7) * (nb >> 3) + (id >> 3);
        bxi = tile % gx; byi = tile / gx;
    }
    const int bm = byi * BM;
    const int bn = bxi * BN;

    const int tid  = threadIdx.x;
    const int lane = tid & 63;
    const int w    = tid >> 6;
    const int wr   = w >> 1, wc = w & 1;           // wave grid 2x2, tile 64x64
    const int l15  = lane & 15, quad = lane >> 4;

    const int gRow = tid >> 2;
    const int kc8  = (tid & 3) * 8;
    const __hip_bfloat16* gsrc[4];
    int ldsoff[4];
    #pragma unroll
    for (int rr = 0; rr < 4; ++rr) {
        const int gr = gRow + 64 * rr;             // 0..255
        if (gr < BM) {
            int ar = bm + gr; if (ar >= M) ar = M - 1;
            gsrc[rr] = A + (size_t)ar * K + kc8;
        } else {
            gsrc[rr] = WT + (size_t)(bn + gr - BM) * K + kc8;
        }
        ldsoff[rr] = gr * BKc + kc8;
    }

    f32x4 acc[4][4];
    #pragma unroll
    for (int i = 0; i < 4; ++i)
        #pragma unroll
        for (int j = 0; j < 4; ++j) acc[i][j] = (f32x4)0.f;

    const int T = K / BKc;
    #pragma unroll
    for (int rr = 0; rr < 4; ++rr) async16(gsrc[rr], smem + ldsoff[rr]);

    for (int it = 0; it < T; ++it) {
        __syncthreads();
        if (it + 1 < T) {
            const int nxt = ((it + 1) & 1) * SMX;
            const int ko  = (it + 1) * BKc;
            #pragma unroll
            for (int rr = 0; rr < 4; ++rr) async16(gsrc[rr] + ko, smem + nxt + ldsoff[rr]);
        }
        const __hip_bfloat16* sA = smem + (it & 1) * SMX;
        const __hip_bfloat16* sB = sA + BM * BKc;

        bf16x8 a[4], b[4];
        #pragma unroll
        for (int mt = 0; mt < 4; ++mt)
            a[mt] = *(const bf16x8*)&sA[(wr * 64 + mt * 16 + l15) * BKc + quad * 8];
        #pragma unroll
        for (int nt = 0; nt < 4; ++nt)
            b[nt] = *(const bf16x8*)&sB[(wc * 64 + nt * 16 + l15) * BKc + quad * 8];
        #pragma unroll
        for (int mt = 0; mt < 4; ++mt)
            #pragma unroll
            for (int nt = 0; nt < 4; ++nt)
                acc[mt][nt] = __builtin_amdgcn_mfma_f32_16x16x32_bf16(
                    a[mt], b[nt], acc[mt][nt], 0, 0, 0);
    }

    #pragma unroll
    for (int mt = 0; mt < 4; ++mt) {
        #pragma unroll
        for (int nt = 0; nt < 4; ++nt) {
            const int col = bn + wc * 64 + nt * 16 + l15;
            const float bz = bias[col];
            #pragma unroll
            for (int r = 0; r < 4; ++r) {
                const int row = bm + wr * 64 + mt * 16 + quad * 4 + r;
                if (row >= M) continue;
                float vv = acc[mt][nt][r] + bz;
                if (MODE == 1) {
                    if (col < 256) {
                        const int b = (row >= NKEYS) ? 1 : 0;
                        const int h = col >> 5, d = col & 31;
                        o_vb[((size_t)(b * 7 + h) * NKEYS + row) * 32 + d] = __float2bfloat16(vv);
                    } else if (col < 512) {
                        o_off[(size_t)row * 256 + (col - 256)] = __float2bfloat16(vv);
                    } else {
                        o_aw[(size_t)row * 128 + (col - 512)] = __float2bfloat16(vv);
                    }
                } else {
                    if (MODE == 3) vv = fmaxf(vv, 0.f);
                    Cout[(size_t)row * N + col] = __float2bfloat16(vv);
                }
            }
        }
    }
}

// ---------------- fused GEMM + residual(bf16) + LayerNorm ----------------
// BM=64 x BN=256 (full row), waves 1x4 (tile 64x64), dbuf 40 KB.
// R14 change: min 4 waves/EU (was 2) -> 4 blocks/CU; VGPR capped at 128 (acc=64, fits).
template<int FINAL>
__global__ __launch_bounds__(256, 4) void gemm_ln_k(
    const __hip_bfloat16* __restrict__ A, const __hip_bfloat16* __restrict__ WT,
    const float* __restrict__ bias, const __hip_bfloat16* __restrict__ xres,
    const float* __restrict__ g, const float* __restrict__ bta,
    float* __restrict__ xfout, __hip_bfloat16* __restrict__ xbout,
    int M, int K)
{
    constexpr int BM = 64, BN = 256, BKc = 32;
    constexpr int ROWS = BM + BN;          // 320
    constexpr int SMX = ROWS * BKc;        // 10240 elems = 20 KB / buffer
    __shared__ __hip_bfloat16 smem[2 * SMX];  // 40 KB

    const int tid  = threadIdx.x;
    const int bm   = blockIdx.x * BM;
    const int lane = tid & 63;
    const int w    = tid >> 6;
    const int l15  = lane & 15, quad = lane >> 4;

    const int gRow = tid >> 2;
    const int kc8  = (tid & 3) * 8;
    const __hip_bfloat16* gsrc[5];
    int ldsoff[5];
    #pragma unroll
    for (int rr = 0; rr < 5; ++rr) {
        const int gr = gRow + 64 * rr;     // 0..319
        if (gr < BM) {
            int ar = bm + gr; if (ar >= M) ar = M - 1;
            gsrc[rr] = A + (size_t)ar * K + kc8;
        } else {
            gsrc[rr] = WT + (size_t)(gr - BM) * K + kc8;
        }
        ldsoff[rr] = gr * BKc + kc8;
    }

    f32x4 acc[4][4];
    #pragma unroll
    for (int i = 0; i < 4; ++i)
        #pragma unroll
        for (int j = 0; j < 4; ++j) acc[i][j] = (f32x4)0.f;

    const int T = K / BKc;
    #pragma unroll
    for (int rr = 0; rr < 5; ++rr) async16(gsrc[rr], smem + ldsoff[rr]);

    for (int it = 0; it < T; ++it) {
        __syncthreads();
        if (it + 1 < T) {
            const int nxt = ((it + 1) & 1) * SMX;
            const int ko  = (it + 1) * BKc;
            #pragma unroll
            for (int rr = 0; rr < 5; ++rr) async16(gsrc[rr] + ko, smem + nxt + ldsoff[rr]);
        }
        const __hip_bfloat16* sA = smem + (it & 1) * SMX;
        const __hip_bfloat16* sB = sA + BM * BKc;

        bf16x8 a[4], b[4];
        #pragma unroll
        for (int mt = 0; mt < 4; ++mt)
            a[mt] = *(const bf16x8*)&sA[(mt * 16 + l15) * BKc + quad * 8];
        #pragma unroll
        for (int nt = 0; nt < 4; ++nt)
            b[nt] = *(const bf16x8*)&sB[(w * 64 + nt * 16 + l15) * BKc + quad * 8];
        #pragma unroll
        for (int mt = 0; mt < 4; ++mt)
            #pragma unroll
            for (int nt = 0; nt < 4; ++nt)
                acc[mt][nt] = __builtin_amdgcn_mfma_f32_16x16x32_bf16(
                    a[mt], b[nt], acc[mt][nt], 0, 0, 0);
    }

    const int colb = w * 64;
    float bz[4], gz[4], bb[4];
    #pragma unroll
    for (int nt = 0; nt < 4; ++nt) {
        const int col = colb + nt * 16 + l15;
        bz[nt] = bias[col]; gz[nt] = g[col]; bb[nt] = bta[col];
    }
    #pragma unroll
    for (int mt = 0; mt < 4; ++mt)
        #pragma unroll
        for (int r = 0; r < 4; ++r) {
            int row = bm + mt * 16 + quad * 4 + r;
            if (row >= M) row = M - 1;
            #pragma unroll
            for (int nt = 0; nt < 4; ++nt)
                acc[mt][nt][r] += bz[nt] + __bfloat162float(
                    xres[(size_t)row * 256 + colb + nt * 16 + l15]);
        }

    __syncthreads();
    float* stats = (float*)smem;
    #pragma unroll
    for (int mt = 0; mt < 4; ++mt)
        #pragma unroll
        for (int r = 0; r < 4; ++r) {
            float s = 0.f, sq = 0.f;
            #pragma unroll
            for (int nt = 0; nt < 4; ++nt) {
                const float v = acc[mt][nt][r];
                s += v; sq += v * v;
            }
            #pragma unroll
            for (int m = 1; m < 16; m <<= 1) {
                s  += __shfl_xor(s,  m, 64);
                sq += __shfl_xor(sq, m, 64);
            }
            if (l15 == 0) {
                const int rl = mt * 16 + quad * 4 + r;
                stats[(w * 64 + rl) * 2 + 0] = s;
                stats[(w * 64 + rl) * 2 + 1] = sq;
            }
        }
    __syncthreads();

    #pragma unroll
    for (int mt = 0; mt < 4; ++mt)
        #pragma unroll
        for (int r = 0; r < 4; ++r) {
            const int rl  = mt * 16 + quad * 4 + r;
            const int row = bm + rl;
            float s  = stats[rl * 2]          + stats[(64 + rl) * 2]
                     + stats[(128 + rl) * 2]  + stats[(192 + rl) * 2];
            float sq = stats[rl * 2 + 1]      + stats[(64 + rl) * 2 + 1]
                     + stats[(128 + rl) * 2 + 1] + stats[(192 + rl) * 2 + 1];
            const float mean = s * (1.f / 256.f);
            const float var  = sq * (1.f / 256.f) - mean * mean;
            const float rstd = rsqrtf(var + EPSV);
            if (row < M) {
                #pragma unroll
                for (int nt = 0; nt < 4; ++nt) {
                    const int col = colb + nt * 16 + l15;
                    const float v = (acc[mt][nt][r] - mean) * rstd * gz[nt] + bb[nt];
                    xbout[(size_t)row * 256 + col] = __float2bfloat16(v);
                    if (FINAL) xfout[(size_t)row * 256 + col] = v;
                }
            }
        }
}

// ---------------- weight transpose+convert ----------------
__global__ void convert_wt_k(const float* __restrict__ W, __hip_bfloat16* __restrict__ WT,
                             int K, int N, int rowOff)
{
    const int idx = blockIdx.x * 256 + threadIdx.x;
    if (idx >= K * N) return;
    const int k = idx / N, n = idx % N;
    WT[(size_t)(rowOff + n) * K + k] = __float2bfloat16(W[idx]);
}

__global__ void pack_bias_k(const float* __restrict__ bv, const float* __restrict__ boff,
                            const float* __restrict__ baw, float* __restrict__ dst)
{
    const int i = blockIdx.x * 256 + threadIdx.x;
    if (i < 256) dst[i] = bv[i];
    else if (i < 512) dst[i] = boff[i - 256];
    else if (i < 640) dst[i] = baw[i - 512];
}

__global__ void convert_src_k(const float* __restrict__ src, __hip_bfloat16* __restrict__ xb)
{
    const int i = blockIdx.x * 256 + threadIdx.x;
    const float4 v = ((const float4*)src)[i];
    xb[i * 4 + 0] = __float2bfloat16(v.x);
    xb[i * 4 + 1] = __float2bfloat16(v.y);
    xb[i * 4 + 2] = __float2bfloat16(v.z);
    xb[i * 4 + 3] = __float2bfloat16(v.w);
}

// ---------------- deformable-attention sampling: R13 (proven plateau) ----------------
__global__ __launch_bounds__(256) void sample_k(
    const __hip_bfloat16* __restrict__ v_bf, // (B*8, NKEYS, 32) bf16 head-major
    const __hip_bfloat16* __restrict__ offb, // (M,256) bf16
    const __hip_bfloat16* __restrict__ awb,  // (M,128) bf16
    const float* __restrict__ ref,           // (M,4,2)
    __hip_bfloat16* __restrict__ out)        // (M,256)
{
    __shared__ alignas(16) float sw[272][4];
    __shared__ alignas(16) int   sa[272][4];
    const int t  = threadIdx.x;
    const int q0 = blockIdx.x * 2;
    const int qi = t >> 7, h = (t >> 4) & 7;

    // ---- phase 1: (qi, h, i) ----
    {
        const int i = t & 15;
        const int q = q0 + qi;
        const int l = i >> 2;
        const float logit = __bfloat162float(awb[(size_t)q * 128 + h * 16 + i]);
        float mx = logit;
        #pragma unroll
        for (int m = 1; m < 16; m <<= 1) mx = fmaxf(mx, __shfl_xor(mx, m, 64));
        const float e = __expf(logit - mx);
        float s = e;
        #pragma unroll
        for (int m = 1; m < 16; m <<= 1) s += __shfl_xor(s, m, 64);
        const float aw = e / s;

        const int ww = (l == 0) ? 100 : (l == 1) ? 50 : (l == 2) ? 25 : 13;
        const int ls = (l == 0) ? 0 : (l == 1) ? 10000 : (l == 2) ? 12500 : 13125;
        const int b  = (q >= NKEYS) ? 1 : 0;
        const int slab = (b * 8 + h) * NKEYS + ls;

        const __hip_bfloat162 ofp = *(const __hip_bfloat162*)&offb[(size_t)q * 256 + h * 32 + i * 2];
        const float2 rf = *(const float2*)&ref[(size_t)q * 8 + l * 2];
        const float x = rf.x * (float)ww + __bfloat162float(ofp.x) - 0.5f;
        const float y = rf.y * (float)ww + __bfloat162float(ofp.y) - 0.5f;  // ww==hh per level
        const float x0f = floorf(x), y0f = floorf(y);
        const float lx = x - x0f, ly = y - y0f;
        const int x0 = (int)x0f, y0 = (int)y0f;
        const bool x0ok = (x0 >= 0) & (x0 < ww);
        const bool x1ok = (x0 + 1 >= 0) & (x0 + 1 < ww);
        const bool y0ok = (y0 >= 0) & (y0 < ww);
        const bool y1ok = (y0 + 1 >= 0) & (y0 + 1 < ww);

        float w00 = (1.f - lx) * (1.f - ly) * aw;
        float w01 = lx * (1.f - ly) * aw;
        float w10 = (1.f - lx) * ly * aw;
        float w11 = lx * ly * aw;
        int a00 = slab + y0 * ww + x0;
        int a01 = a00 + 1;
        int a10 = a00 + ww;
        int a11 = a10 + 1;
        if (!(y0ok & x0ok)) { w00 = 0.f; a00 = 0; }
        if (!(y0ok & x1ok)) { w01 = 0.f; a01 = 0; }
        if (!(y1ok & x0ok)) { w10 = 0.f; a10 = 0; }
        if (!(y1ok & x1ok)) { w11 = 0.f; a11 = 0; }

        const int idx = (qi * 8 + h) * 17 + i;
        sw[idx][0] = w00; sw[idx][1] = w01; sw[idx][2] = w10; sw[idx][3] = w11;
        sa[idx][0] = a00 * 64; sa[idx][1] = a01 * 64;   // byte offsets (row = 64 B)
        sa[idx][2] = a10 * 64; sa[idx][3] = a11 * 64;
    }
    __syncthreads();

    // ---- phase 2: (qi, h, dim-pair d2) ----
    const int d2 = t & 15;
    const unsigned d4 = d2 * 4;
    const char* vb = (const char*)v_bf;
    const int ebase = (qi * 8 + h) * 17;
    f32x2 acc = (f32x2)0.f;
    #pragma unroll
    for (int i = 0; i < 16; ++i) {
        const f32x4 wv = *(const f32x4*)sw[ebase + i];
        const int4  av = *(const int4*)sa[ebase + i];
        const unsigned p0 = *(const unsigned*)(vb + ((unsigned)av.x + d4));
        const unsigned p1 = *(const unsigned*)(vb + ((unsigned)av.y + d4));
        const unsigned p2 = *(const unsigned*)(vb + ((unsigned)av.z + d4));
        const unsigned p3 = *(const unsigned*)(vb + ((unsigned)av.w + d4));
        f32x2 v;
        v[0] = __uint_as_float(p0 << 16); v[1] = __uint_as_float(p0 & 0xffff0000u);
        acc += (f32x2)(wv[0]) * v;
        v[0] = __uint_as_float(p1 << 16); v[1] = __uint_as_float(p1 & 0xffff0000u);
        acc += (f32x2)(wv[1]) * v;
        v[0] = __uint_as_float(p2 << 16); v[1] = __uint_as_float(p2 & 0xffff0000u);
        acc += (f32x2)(wv[2]) * v;
        v[0] = __uint_as_float(p3 << 16); v[1] = __uint_as_float(p3 & 0xffff0000u);
        acc += (f32x2)(wv[3]) * v;
    }
    __hip_bfloat162 ov;
    ov.x = __float2bfloat16(acc[0]);
    ov.y = __float2bfloat16(acc[1]);
    *(__hip_bfloat162*)&out[(size_t)(q0 + qi) * 256 + h * 32 + d2 * 2] = ov;
}

// ---------------- host ----------------
extern "C" void kernel_launch(void* const* d_in, const int* in_sizes, int n_in,
                              void* d_out, int out_size, void* d_ws, size_t ws_size,
                              hipStream_t stream)
{
    const float* src  = (const float*)d_in[0];
    const float* ref  = (const float*)d_in[1];
    const float* Woff = (const float*)d_in[4];
    const float* boff = (const float*)d_in[5];
    const float* Waw  = (const float*)d_in[6];
    const float* baw  = (const float*)d_in[7];
    const float* Wv   = (const float*)d_in[8];
    const float* bv   = (const float*)d_in[9];
    const float* Wo   = (const float*)d_in[10];
    const float* bo   = (const float*)d_in[11];
    const float* ln1g = (const float*)d_in[12];
    const float* ln1b = (const float*)d_in[13];
    const float* Wf1  = (const float*)d_in[14];
    const float* bf1  = (const float*)d_in[15];
    const float* Wf2  = (const float*)d_in[16];
    const float* bf2  = (const float*)d_in[17];
    const float* ln2g = (const float*)d_in[18];
    const float* ln2b = (const float*)d_in[19];

    float* x = (float*)d_out;

    float* ws = (float*)d_ws;
    float* bias1 = ws;                                    // 640 f32
    __hip_bfloat16* v_bf  = (__hip_bfloat16*)(bias1 + 640);
    __hip_bfloat16* offb  = v_bf  + (size_t)MROWS * 256;
    __hip_bfloat16* awb   = offb  + (size_t)MROWS * 256;
    __hip_bfloat16* xb    = awb   + (size_t)MROWS * 128;
    __hip_bfloat16* attnb = xb    + (size_t)MROWS * 256;
    __hip_bfloat16* hb    = attnb + (size_t)MROWS * 256;
    __hip_bfloat16* WT1   = hb    + (size_t)MROWS * 1024;
    __hip_bfloat16* WTo   = WT1   + 640 * 256;
    __hip_bfloat16* WTf1  = WTo   + 256 * 256;
    __hip_bfloat16* WTf2  = WTf1  + 1024 * 256;

    convert_wt_k<<<(256 * 256 + 255) / 256, 256, 0, stream>>>(Wv,   WT1,  256, 256,   0);
    convert_wt_k<<<(256 * 256 + 255) / 256, 256, 0, stream>>>(Woff, WT1,  256, 256, 256);
    convert_wt_k<<<(256 * 128 + 255) / 256, 256, 0, stream>>>(Waw,  WT1,  256, 128, 512);
    convert_wt_k<<<(256 * 256 + 255) / 256, 256, 0, stream>>>(Wo,   WTo,  256, 256,   0);
    convert_wt_k<<<(256 * 1024 + 255) / 256, 256, 0, stream>>>(Wf1, WTf1, 256, 1024,  0);
    convert_wt_k<<<(1024 * 256 + 255) / 256, 256, 0, stream>>>(Wf2, WTf2, 1024, 256,  0);
    pack_bias_k<<<3, 256, 0, stream>>>(bv, boff, baw, bias1);
    convert_src_k<<<(MROWS * 64 + 255) / 256, 256, 0, stream>>>(src, xb);

    const int gy  = (MROWS + 127) / 128;  // 208
    const int gln = (MROWS + 63) / 64;    // 416
    for (int layer = 0; layer < 6; ++layer) {
        gemm_mfma_k<1><<<dim3(640 / 128, gy), 256, 0, stream>>>(
            xb, WT1, bias1, nullptr, MROWS, 640, 256, v_bf, offb, awb);
        sample_k<<<MROWS / 2, 256, 0, stream>>>(v_bf, offb, awb, ref, attnb);
        gemm_ln_k<0><<<gln, 256, 0, stream>>>(
            attnb, WTo, bo, xb, ln1g, ln1b, nullptr, xb, MROWS, 256);
        gemm_mfma_k<3><<<dim3(1024 / 128, gy), 256, 0, stream>>>(
            xb, WTf1, bf1, hb, MROWS, 1024, 256, nullptr, nullptr, nullptr);
        if (layer < 5)
            gemm_ln_k<0><<<gln, 256, 0, stream>>>(
                hb, WTf2, bf2, xb, ln2g, ln2b, nullptr, xb, MROWS, 1024);
        else
            gemm_ln_k<1><<<gln, 256, 0, stream>>>(
                hb, WTf2, bf2, xb, ln2g, ln2b, x, xb, MROWS, 1024);
    }
}

// Round 15
// 1073.103 us; speedup vs baseline: 1.1976x; 1.1976x over previous
//
#include <hip/hip_runtime.h>
#include <hip/hip_bf16.h>
#include <math.h>

// ---------------- static problem config ----------------
#define NKEYS 13294
#define BATCH 2
#define MROWS (BATCH * NKEYS)   // 26588
#define EDIM  256
#define FDIM  1024
#define EPSV  1e-5f

typedef __bf16 bf16x8 __attribute__((ext_vector_type(8)));
typedef float  f32x4  __attribute__((ext_vector_type(4)));
typedef float  f32x2  __attribute__((ext_vector_type(2)));

__device__ __forceinline__ void async16(const void* g, void* l) {
    __builtin_amdgcn_global_load_lds(
        (const __attribute__((address_space(1))) void*)g,
        (__attribute__((address_space(3))) void*)l, 16, 0, 0);
}

// ---------------- bf16 MFMA GEMM (BM=128 x BN=128, waves 2x2 of 64x64, dbuf) ----------------
// XCD swizzle kept (~90 us aggregate win, R10/R11).
// MODE 1: split fused store (N=640): col<256 -> v_bf head-major bf16;
//         col<512 -> o_off bf16 (stride 256); else -> o_aw bf16 (stride 128).
// MODE 3: bf16 out + ReLU (stride N).
template<int MODE>
__global__ __launch_bounds__(256, 4) void gemm_mfma_k(
    const __hip_bfloat16* __restrict__ A, const __hip_bfloat16* __restrict__ WT,
    const float* __restrict__ bias, __hip_bfloat16* __restrict__ Cout,
    int M, int N, int K,
    __hip_bfloat16* __restrict__ o_vb, __hip_bfloat16* __restrict__ o_off,
    __hip_bfloat16* __restrict__ o_aw)
{
    constexpr int BM = 128, BN = 128, BKc = 32;
    constexpr int SMX = (BM + BN) * BKc;           // 8192 elems = 16 KB / buffer
    __shared__ __hip_bfloat16 smem[2 * SMX];       // 32 KB

    // ---- XCD-aware tile swizzle ----
    const int gx = gridDim.x, nb = gx * gridDim.y;
    int bxi = blockIdx.x, byi = blockIdx.y;
    if ((nb & 7) == 0) {
        const int id   = byi * gx + bxi;
        const int tile = (id & 7) * (nb >> 3) + (id >> 3);
        bxi = tile % gx; byi = tile / gx;
    }
    const int bm = byi * BM;
    const int bn = bxi * BN;

    const int tid  = threadIdx.x;
    const int lane = tid & 63;
    const int w    = tid >> 6;
    const int wr   = w >> 1, wc = w & 1;           // wave grid 2x2, tile 64x64
    const int l15  = lane & 15, quad = lane >> 4;

    const int gRow = tid >> 2;
    const int kc8  = (tid & 3) * 8;
    const __hip_bfloat16* gsrc[4];
    int ldsoff[4];
    #pragma unroll
    for (int rr = 0; rr < 4; ++rr) {
        const int gr = gRow + 64 * rr;             // 0..255
        if (gr < BM) {
            int ar = bm + gr; if (ar >= M) ar = M - 1;
            gsrc[rr] = A + (size_t)ar * K + kc8;
        } else {
            gsrc[rr] = WT + (size_t)(bn + gr - BM) * K + kc8;
        }
        ldsoff[rr] = gr * BKc + kc8;
    }

    f32x4 acc[4][4];
    #pragma unroll
    for (int i = 0; i < 4; ++i)
        #pragma unroll
        for (int j = 0; j < 4; ++j) acc[i][j] = (f32x4)0.f;

    const int T = K / BKc;
    #pragma unroll
    for (int rr = 0; rr < 4; ++rr) async16(gsrc[rr], smem + ldsoff[rr]);

    for (int it = 0; it < T; ++it) {
        __syncthreads();
        if (it + 1 < T) {
            const int nxt = ((it + 1) & 1) * SMX;
            const int ko  = (it + 1) * BKc;
            #pragma unroll
            for (int rr = 0; rr < 4; ++rr) async16(gsrc[rr] + ko, smem + nxt + ldsoff[rr]);
        }
        const __hip_bfloat16* sA = smem + (it & 1) * SMX;
        const __hip_bfloat16* sB = sA + BM * BKc;

        bf16x8 a[4], b[4];
        #pragma unroll
        for (int mt = 0; mt < 4; ++mt)
            a[mt] = *(const bf16x8*)&sA[(wr * 64 + mt * 16 + l15) * BKc + quad * 8];
        #pragma unroll
        for (int nt = 0; nt < 4; ++nt)
            b[nt] = *(const bf16x8*)&sB[(wc * 64 + nt * 16 + l15) * BKc + quad * 8];
        #pragma unroll
        for (int mt = 0; mt < 4; ++mt)
            #pragma unroll
            for (int nt = 0; nt < 4; ++nt)
                acc[mt][nt] = __builtin_amdgcn_mfma_f32_16x16x32_bf16(
                    a[mt], b[nt], acc[mt][nt], 0, 0, 0);
    }

    #pragma unroll
    for (int mt = 0; mt < 4; ++mt) {
        #pragma unroll
        for (int nt = 0; nt < 4; ++nt) {
            const int col = bn + wc * 64 + nt * 16 + l15;
            const float bz = bias[col];
            #pragma unroll
            for (int r = 0; r < 4; ++r) {
                const int row = bm + wr * 64 + mt * 16 + quad * 4 + r;
                if (row >= M) continue;
                float vv = acc[mt][nt][r] + bz;
                if (MODE == 1) {
                    if (col < 256) {
                        const int b = (row >= NKEYS) ? 1 : 0;
                        const int h = col >> 5, d = col & 31;
                        o_vb[((size_t)(b * 7 + h) * NKEYS + row) * 32 + d] = __float2bfloat16(vv);
                    } else if (col < 512) {
                        o_off[(size_t)row * 256 + (col - 256)] = __float2bfloat16(vv);
                    } else {
                        o_aw[(size_t)row * 128 + (col - 512)] = __float2bfloat16(vv);
                    }
                } else {
                    if (MODE == 3) vv = fmaxf(vv, 0.f);
                    Cout[(size_t)row * N + col] = __float2bfloat16(vv);
                }
            }
        }
    }
}

// ---------------- fused GEMM + residual(bf16) + LayerNorm ----------------
// BM=64 x BN=256 (full row), waves 1x4 (tile 64x64), dbuf 40 KB.
// (256,2): LDS is the occupancy limiter; (256,4) forced VGPR 88->64 and spilled (R14).
template<int FINAL>
__global__ __launch_bounds__(256, 2) void gemm_ln_k(
    const __hip_bfloat16* __restrict__ A, const __hip_bfloat16* __restrict__ WT,
    const float* __restrict__ bias, const __hip_bfloat16* __restrict__ xres,
    const float* __restrict__ g, const float* __restrict__ bta,
    float* __restrict__ xfout, __hip_bfloat16* __restrict__ xbout,
    int M, int K)
{
    constexpr int BM = 64, BN = 256, BKc = 32;
    constexpr int ROWS = BM + BN;          // 320
    constexpr int SMX = ROWS * BKc;        // 10240 elems = 20 KB / buffer
    __shared__ __hip_bfloat16 smem[2 * SMX];  // 40 KB

    const int tid  = threadIdx.x;
    const int bm   = blockIdx.x * BM;
    const int lane = tid & 63;
    const int w    = tid >> 6;
    const int l15  = lane & 15, quad = lane >> 4;

    const int gRow = tid >> 2;
    const int kc8  = (tid & 3) * 8;
    const __hip_bfloat16* gsrc[5];
    int ldsoff[5];
    #pragma unroll
    for (int rr = 0; rr < 5; ++rr) {
        const int gr = gRow + 64 * rr;     // 0..319
        if (gr < BM) {
            int ar = bm + gr; if (ar >= M) ar = M - 1;
            gsrc[rr] = A + (size_t)ar * K + kc8;
        } else {
            gsrc[rr] = WT + (size_t)(gr - BM) * K + kc8;
        }
        ldsoff[rr] = gr * BKc + kc8;
    }

    f32x4 acc[4][4];
    #pragma unroll
    for (int i = 0; i < 4; ++i)
        #pragma unroll
        for (int j = 0; j < 4; ++j) acc[i][j] = (f32x4)0.f;

    const int T = K / BKc;
    #pragma unroll
    for (int rr = 0; rr < 5; ++rr) async16(gsrc[rr], smem + ldsoff[rr]);

    for (int it = 0; it < T; ++it) {
        __syncthreads();
        if (it + 1 < T) {
            const int nxt = ((it + 1) & 1) * SMX;
            const int ko  = (it + 1) * BKc;
            #pragma unroll
            for (int rr = 0; rr < 5; ++rr) async16(gsrc[rr] + ko, smem + nxt + ldsoff[rr]);
        }
        const __hip_bfloat16* sA = smem + (it & 1) * SMX;
        const __hip_bfloat16* sB = sA + BM * BKc;

        bf16x8 a[4], b[4];
        #pragma unroll
        for (int mt = 0; mt < 4; ++mt)
            a[mt] = *(const bf16x8*)&sA[(mt * 16 + l15) * BKc + quad * 8];
        #pragma unroll
        for (int nt = 0; nt < 4; ++nt)
            b[nt] = *(const bf16x8*)&sB[(w * 64 + nt * 16 + l15) * BKc + quad * 8];
        #pragma unroll
        for (int mt = 0; mt < 4; ++mt)
            #pragma unroll
            for (int nt = 0; nt < 4; ++nt)
                acc[mt][nt] = __builtin_amdgcn_mfma_f32_16x16x32_bf16(
                    a[mt], b[nt], acc[mt][nt], 0, 0, 0);
    }

    const int colb = w * 64;
    float bz[4], gz[4], bb[4];
    #pragma unroll
    for (int nt = 0; nt < 4; ++nt) {
        const int col = colb + nt * 16 + l15;
        bz[nt] = bias[col]; gz[nt] = g[col]; bb[nt] = bta[col];
    }
    #pragma unroll
    for (int mt = 0; mt < 4; ++mt)
        #pragma unroll
        for (int r = 0; r < 4; ++r) {
            int row = bm + mt * 16 + quad * 4 + r;
            if (row >= M) row = M - 1;
            #pragma unroll
            for (int nt = 0; nt < 4; ++nt)
                acc[mt][nt][r] += bz[nt] + __bfloat162float(
                    xres[(size_t)row * 256 + colb + nt * 16 + l15]);
        }

    __syncthreads();
    float* stats = (float*)smem;
    #pragma unroll
    for (int mt = 0; mt < 4; ++mt)
        #pragma unroll
        for (int r = 0; r < 4; ++r) {
            float s = 0.f, sq = 0.f;
            #pragma unroll
            for (int nt = 0; nt < 4; ++nt) {
                const float v = acc[mt][nt][r];
                s += v; sq += v * v;
            }
            #pragma unroll
            for (int m = 1; m < 16; m <<= 1) {
                s  += __shfl_xor(s,  m, 64);
                sq += __shfl_xor(sq, m, 64);
            }
            if (l15 == 0) {
                const int rl = mt * 16 + quad * 4 + r;
                stats[(w * 64 + rl) * 2 + 0] = s;
                stats[(w * 64 + rl) * 2 + 1] = sq;
            }
        }
    __syncthreads();

    #pragma unroll
    for (int mt = 0; mt < 4; ++mt)
        #pragma unroll
        for (int r = 0; r < 4; ++r) {
            const int rl  = mt * 16 + quad * 4 + r;
            const int row = bm + rl;
            float s  = stats[rl * 2]          + stats[(64 + rl) * 2]
                     + stats[(128 + rl) * 2]  + stats[(192 + rl) * 2];
            float sq = stats[rl * 2 + 1]      + stats[(64 + rl) * 2 + 1]
                     + stats[(128 + rl) * 2 + 1] + stats[(192 + rl) * 2 + 1];
            const float mean = s * (1.f / 256.f);
            const float var  = sq * (1.f / 256.f) - mean * mean;
            const float rstd = rsqrtf(var + EPSV);
            if (row < M) {
                #pragma unroll
                for (int nt = 0; nt < 4; ++nt) {
                    const int col = colb + nt * 16 + l15;
                    const float v = (acc[mt][nt][r] - mean) * rstd * gz[nt] + bb[nt];
                    xbout[(size_t)row * 256 + col] = __float2bfloat16(v);
                    if (FINAL) xfout[(size_t)row * 256 + col] = v;
                }
            }
        }
}

// ---------------- weight transpose+convert ----------------
__global__ void convert_wt_k(const float* __restrict__ W, __hip_bfloat16* __restrict__ WT,
                             int K, int N, int rowOff)
{
    const int idx = blockIdx.x * 256 + threadIdx.x;
    if (idx >= K * N) return;
    const int k = idx / N, n = idx % N;
    WT[(size_t)(rowOff + n) * K + k] = __float2bfloat16(W[idx]);
}

__global__ void pack_bias_k(const float* __restrict__ bv, const float* __restrict__ boff,
                            const float* __restrict__ baw, float* __restrict__ dst)
{
    const int i = blockIdx.x * 256 + threadIdx.x;
    if (i < 256) dst[i] = bv[i];
    else if (i < 512) dst[i] = boff[i - 256];
    else if (i < 640) dst[i] = baw[i - 512];
}

__global__ void convert_src_k(const float* __restrict__ src, __hip_bfloat16* __restrict__ xb)
{
    const int i = blockIdx.x * 256 + threadIdx.x;
    const float4 v = ((const float4*)src)[i];
    xb[i * 4 + 0] = __float2bfloat16(v.x);
    xb[i * 4 + 1] = __float2bfloat16(v.y);
    xb[i * 4 + 2] = __float2bfloat16(v.z);
    xb[i * 4 + 3] = __float2bfloat16(v.w);
}

// ---------------- deformable-attention sampling: R13 (proven plateau) ----------------
__global__ __launch_bounds__(256) void sample_k(
    const __hip_bfloat16* __restrict__ v_bf, // (B*8, NKEYS, 32) bf16 head-major
    const __hip_bfloat16* __restrict__ offb, // (M,256) bf16
    const __hip_bfloat16* __restrict__ awb,  // (M,128) bf16
    const float* __restrict__ ref,           // (M,4,2)
    __hip_bfloat16* __restrict__ out)        // (M,256)
{
    __shared__ alignas(16) float sw[272][4];
    __shared__ alignas(16) int   sa[272][4];
    const int t  = threadIdx.x;
    const int q0 = blockIdx.x * 2;
    const int qi = t >> 7, h = (t >> 4) & 7;

    // ---- phase 1: (qi, h, i) ----
    {
        const int i = t & 15;
        const int q = q0 + qi;
        const int l = i >> 2;
        const float logit = __bfloat162float(awb[(size_t)q * 128 + h * 16 + i]);
        float mx = logit;
        #pragma unroll
        for (int m = 1; m < 16; m <<= 1) mx = fmaxf(mx, __shfl_xor(mx, m, 64));
        const float e = __expf(logit - mx);
        float s = e;
        #pragma unroll
        for (int m = 1; m < 16; m <<= 1) s += __shfl_xor(s, m, 64);
        const float aw = e / s;

        const int ww = (l == 0) ? 100 : (l == 1) ? 50 : (l == 2) ? 25 : 13;
        const int ls = (l == 0) ? 0 : (l == 1) ? 10000 : (l == 2) ? 12500 : 13125;
        const int b  = (q >= NKEYS) ? 1 : 0;
        const int slab = (b * 8 + h) * NKEYS + ls;

        const __hip_bfloat162 ofp = *(const __hip_bfloat162*)&offb[(size_t)q * 256 + h * 32 + i * 2];
        const float2 rf = *(const float2*)&ref[(size_t)q * 8 + l * 2];
        const float x = rf.x * (float)ww + __bfloat162float(ofp.x) - 0.5f;
        const float y = rf.y * (float)ww + __bfloat162float(ofp.y) - 0.5f;  // ww==hh per level
        const float x0f = floorf(x), y0f = floorf(y);
        const float lx = x - x0f, ly = y - y0f;
        const int x0 = (int)x0f, y0 = (int)y0f;
        const bool x0ok = (x0 >= 0) & (x0 < ww);
        const bool x1ok = (x0 + 1 >= 0) & (x0 + 1 < ww);
        const bool y0ok = (y0 >= 0) & (y0 < ww);
        const bool y1ok = (y0 + 1 >= 0) & (y0 + 1 < ww);

        float w00 = (1.f - lx) * (1.f - ly) * aw;
        float w01 = lx * (1.f - ly) * aw;
        float w10 = (1.f - lx) * ly * aw;
        float w11 = lx * ly * aw;
        int a00 = slab + y0 * ww + x0;
        int a01 = a00 + 1;
        int a10 = a00 + ww;
        int a11 = a10 + 1;
        if (!(y0ok & x0ok)) { w00 = 0.f; a00 = 0; }
        if (!(y0ok & x1ok)) { w01 = 0.f; a01 = 0; }
        if (!(y1ok & x0ok)) { w10 = 0.f; a10 = 0; }
        if (!(y1ok & x1ok)) { w11 = 0.f; a11 = 0; }

        const int idx = (qi * 8 + h) * 17 + i;
        sw[idx][0] = w00; sw[idx][1] = w01; sw[idx][2] = w10; sw[idx][3] = w11;
        sa[idx][0] = a00 * 64; sa[idx][1] = a01 * 64;   // byte offsets (row = 64 B)
        sa[idx][2] = a10 * 64; sa[idx][3] = a11 * 64;
    }
    __syncthreads();

    // ---- phase 2: (qi, h, dim-pair d2) ----
    const int d2 = t & 15;
    const unsigned d4 = d2 * 4;
    const char* vb = (const char*)v_bf;
    const int ebase = (qi * 8 + h) * 17;
    f32x2 acc = (f32x2)0.f;
    #pragma unroll
    for (int i = 0; i < 16; ++i) {
        const f32x4 wv = *(const f32x4*)sw[ebase + i];
        const int4  av = *(const int4*)sa[ebase + i];
        const unsigned p0 = *(const unsigned*)(vb + ((unsigned)av.x + d4));
        const unsigned p1 = *(const unsigned*)(vb + ((unsigned)av.y + d4));
        const unsigned p2 = *(const unsigned*)(vb + ((unsigned)av.z + d4));
        const unsigned p3 = *(const unsigned*)(vb + ((unsigned)av.w + d4));
        f32x2 v;
        v[0] = __uint_as_float(p0 << 16); v[1] = __uint_as_float(p0 & 0xffff0000u);
        acc += (f32x2)(wv[0]) * v;
        v[0] = __uint_as_float(p1 << 16); v[1] = __uint_as_float(p1 & 0xffff0000u);
        acc += (f32x2)(wv[1]) * v;
        v[0] = __uint_as_float(p2 << 16); v[1] = __uint_as_float(p2 & 0xffff0000u);
        acc += (f32x2)(wv[2]) * v;
        v[0] = __uint_as_float(p3 << 16); v[1] = __uint_as_float(p3 & 0xffff0000u);
        acc += (f32x2)(wv[3]) * v;
    }
    __hip_bfloat162 ov;
    ov.x = __float2bfloat16(acc[0]);
    ov.y = __float2bfloat16(acc[1]);
    *(__hip_bfloat162*)&out[(size_t)(q0 + qi) * 256 + h * 32 + d2 * 2] = ov;
}

// ---------------- host ----------------
extern "C" void kernel_launch(void* const* d_in, const int* in_sizes, int n_in,
                              void* d_out, int out_size, void* d_ws, size_t ws_size,
                              hipStream_t stream)
{
    const float* src  = (const float*)d_in[0];
    const float* ref  = (const float*)d_in[1];
    const float* Woff = (const float*)d_in[4];
    const float* boff = (const float*)d_in[5];
    const float* Waw  = (const float*)d_in[6];
    const float* baw  = (const float*)d_in[7];
    const float* Wv   = (const float*)d_in[8];
    const float* bv   = (const float*)d_in[9];
    const float* Wo   = (const float*)d_in[10];
    const float* bo   = (const float*)d_in[11];
    const float* ln1g = (const float*)d_in[12];
    const float* ln1b = (const float*)d_in[13];
    const float* Wf1  = (const float*)d_in[14];
    const float* bf1  = (const float*)d_in[15];
    const float* Wf2  = (const float*)d_in[16];
    const float* bf2  = (const float*)d_in[17];
    const float* ln2g = (const float*)d_in[18];
    const float* ln2b = (const float*)d_in[19];

    float* x = (float*)d_out;

    float* ws = (float*)d_ws;
    float* bias1 = ws;                                    // 640 f32
    __hip_bfloat16* v_bf  = (__hip_bfloat16*)(bias1 + 640);
    __hip_bfloat16* offb  = v_bf  + (size_t)MROWS * 256;
    __hip_bfloat16* awb   = offb  + (size_t)MROWS * 256;
    __hip_bfloat16* xb    = awb   + (size_t)MROWS * 128;
    __hip_bfloat16* attnb = xb    + (size_t)MROWS * 256;
    __hip_bfloat16* hb    = attnb + (size_t)MROWS * 256;
    __hip_bfloat16* WT1   = hb    + (size_t)MROWS * 1024;
    __hip_bfloat16* WTo   = WT1   + 640 * 256;
    __hip_bfloat16* WTf1  = WTo   + 256 * 256;
    __hip_bfloat16* WTf2  = WTf1  + 1024 * 256;

    convert_wt_k<<<(256 * 256 + 255) / 256, 256, 0, stream>>>(Wv,   WT1,  256, 256,   0);
    convert_wt_k<<<(256 * 256 + 255) / 256, 256, 0, stream>>>(Woff, WT1,  256, 256, 256);
    convert_wt_k<<<(256 * 128 + 255) / 256, 256, 0, stream>>>(Waw,  WT1,  256, 128, 512);
    convert_wt_k<<<(256 * 256 + 255) / 256, 256, 0, stream>>>(Wo,   WTo,  256, 256,   0);
    convert_wt_k<<<(256 * 1024 + 255) / 256, 256, 0, stream>>>(Wf1, WTf1, 256, 1024,  0);
    convert_wt_k<<<(1024 * 256 + 255) / 256, 256, 0, stream>>>(Wf2, WTf2, 1024, 256,  0);
    pack_bias_k<<<3, 256, 0, stream>>>(bv, boff, baw, bias1);
    convert_src_k<<<(MROWS * 64 + 255) / 256, 256, 0, stream>>>(src, xb);

    const int gy  = (MROWS + 127) / 128;  // 208
    const int gln = (MROWS + 63) / 64;    // 416
    for (int layer = 0; layer < 6; ++layer) {
        gemm_mfma_k<1><<<dim3(640 / 128, gy), 256, 0, stream>>>(
            xb, WT1, bias1, nullptr, MROWS, 640, 256, v_bf, offb, awb);
        sample_k<<<MROWS / 2, 256, 0, stream>>>(v_bf, offb, awb, ref, attnb);
        gemm_ln_k<0><<<gln, 256, 0, stream>>>(
            attnb, WTo, bo, xb, ln1g, ln1b, nullptr, xb, MROWS, 256);
        gemm_mfma_k<3><<<dim3(1024 / 128, gy), 256, 0, stream>>>(
            xb, WTf1, bf1, hb, MROWS, 1024, 256, nullptr, nullptr, nullptr);
        if (layer < 5)
            gemm_ln_k<0><<<gln, 256, 0, stream>>>(
                hb, WTf2, bf2, xb, ln2g, ln2b, nullptr, xb, MROWS, 1024);
        else
            gemm_ln_k<1><<<gln, 256, 0, stream>>>(
                hb, WTf2, bf2, xb, ln2g, ln2b, x, xb, MROWS, 1024);
    }
}